// Round 1
// baseline (403.731 us; speedup 1.0000x reference)
//
#include <hip/hip_runtime.h>
#include <math.h>

#define EPS_BN 1e-5f

// ---------------------------------------------------------------------------
// Kernel 1: transpose fc1_w (64,784) -> wt (784,64) so fc1 reads coalesce
// ---------------------------------------------------------------------------
__global__ __launch_bounds__(256) void k_transpose(const float* __restrict__ w,
                                                   float* __restrict__ wt) {
    int t = blockIdx.x * 256 + threadIdx.x;
    if (t < 784 * 64) {
        int k = t >> 6;      // 0..783
        int o = t & 63;      // 0..63
        wt[t] = w[o * 784 + k];
    }
}

// ---------------------------------------------------------------------------
// Kernel 2: per-image conv1+relu+pool, conv2+relu+pool, heads
//   block = 1 image, 256 threads
// ---------------------------------------------------------------------------
__global__ __launch_bounds__(256) void k_conv(
    const float* __restrict__ x,
    const float* __restrict__ c1w, const float* __restrict__ c1b,
    const float* __restrict__ c2w, const float* __restrict__ c2b,
    const float* __restrict__ sw1, const float* __restrict__ sb1,
    const float* __restrict__ sw2, const float* __restrict__ sb2,
    const float* __restrict__ ew1, const float* __restrict__ eb1,
    const float* __restrict__ ew2, const float* __restrict__ eb2,
    const float* __restrict__ ew3, const float* __restrict__ eb3,
    const float* __restrict__ mem,
    float* __restrict__ flat_out, float* __restrict__ out, int bsz)
{
    __shared__ float sx[784];       // 28x28 input image
    __shared__ float s1[1568];      // 8 x 14 x 14 (pooled conv1)
    __shared__ float s2[784];       // 16 x 7 x 7  (pooled conv2 == flat row)
    __shared__ float w1[72];
    __shared__ float b1[8];
    __shared__ float w2[1152];
    __shared__ float b2[16];

    const int tid = threadIdx.x;
    const int img = blockIdx.x;
    const float* xim = x + (size_t)img * 784;

    for (int i = tid; i < 784; i += 256) sx[i] = xim[i];
    if (tid < 72) w1[tid] = c1w[tid];
    if (tid < 8)  b1[tid] = c1b[tid];
    for (int i = tid; i < 1152; i += 256) w2[i] = c2w[i];
    if (tid < 16) b2[tid] = c2b[tid];
    __syncthreads();

    // ---- conv1 3x3 SAME (1->8) + relu + 2x2 maxpool -> s1[c*196 + py*14 + px]
    for (int idx = tid; idx < 1568; idx += 256) {
        int c  = idx / 196;
        int r  = idx - c * 196;
        int py = r / 14;
        int px = r - py * 14;
        int br = 2 * py - 1;
        int bc = 2 * px - 1;
        float win[4][4];
        #pragma unroll
        for (int wy = 0; wy < 4; ++wy) {
            int iy = br + wy;
            bool oy = (unsigned)iy < 28u;
            #pragma unroll
            for (int wx = 0; wx < 4; ++wx) {
                int ix = bc + wx;
                win[wy][wx] = (oy && (unsigned)ix < 28u) ? sx[iy * 28 + ix] : 0.f;
            }
        }
        const float* wp = &w1[c * 9];
        float bb = b1[c];
        float a00 = bb, a01 = bb, a10 = bb, a11 = bb;
        #pragma unroll
        for (int ky = 0; ky < 3; ++ky) {
            #pragma unroll
            for (int kx = 0; kx < 3; ++kx) {
                float wv = wp[ky * 3 + kx];
                a00 += win[ky][kx]     * wv;
                a01 += win[ky][kx + 1] * wv;
                a10 += win[ky + 1][kx] * wv;
                a11 += win[ky + 1][kx + 1] * wv;
            }
        }
        float m = fmaxf(fmaxf(a00, a01), fmaxf(a10, a11));
        s1[idx] = fmaxf(m, 0.f);   // relu-then-pool == pool-then-relu
    }
    __syncthreads();

    // ---- conv2 3x3 SAME (8->16) + relu + 2x2 maxpool -> s2[c*49 + py*7 + px]
    for (int idx = tid; idx < 784; idx += 256) {
        int c  = idx / 49;
        int r  = idx - c * 49;
        int py = r / 7;
        int px = r - py * 7;
        int br = 2 * py - 1;
        int bc = 2 * px - 1;
        float bb = b2[c];
        float a00 = bb, a01 = bb, a10 = bb, a11 = bb;
        for (int ic = 0; ic < 8; ++ic) {
            const float* sp = &s1[ic * 196];
            float win[4][4];
            #pragma unroll
            for (int wy = 0; wy < 4; ++wy) {
                int iy = br + wy;
                bool oy = (unsigned)iy < 14u;
                #pragma unroll
                for (int wx = 0; wx < 4; ++wx) {
                    int ix = bc + wx;
                    win[wy][wx] = (oy && (unsigned)ix < 14u) ? sp[iy * 14 + ix] : 0.f;
                }
            }
            const float* wp = &w2[(c * 8 + ic) * 9];
            #pragma unroll
            for (int ky = 0; ky < 3; ++ky) {
                #pragma unroll
                for (int kx = 0; kx < 3; ++kx) {
                    float wv = wp[ky * 3 + kx];
                    a00 += win[ky][kx]     * wv;
                    a01 += win[ky][kx + 1] * wv;
                    a10 += win[ky + 1][kx] * wv;
                    a11 += win[ky + 1][kx + 1] * wv;
                }
            }
        }
        float m = fmaxf(fmaxf(a00, a01), fmaxf(a10, a11));
        s2[idx] = fmaxf(m, 0.f);
    }
    __syncthreads();

    // ---- write flat row (coalesced)
    float* fo = flat_out + (size_t)img * 784;
    for (int i = tid; i < 784; i += 256) fo[i] = s2[i];

    // ---- tiny heads from flat[:4] (threads 0..11 of wave 0)
    if (tid < 12) {
        const float f0 = s2[0], f1 = s2[1], f2 = s2[2], f3 = s2[3];
        const int off_samp = bsz * 4;
        const int off_reg  = bsz * 6;
        const int off_ker  = bsz * 7;
        if (tid < 10) {
            // RBF kernel row element j = tid
            int j = tid;
            float m0 = mem[j * 4 + 0], m1 = mem[j * 4 + 1];
            float m2 = mem[j * 4 + 2], m3 = mem[j * 4 + 3];
            float sq = f0 * f0 + f1 * f1 + f2 * f2 + f3 * f3
                     + m0 * m0 + m1 * m1 + m2 * m2 + m3 * m3
                     - 2.f * (f0 * m0 + f1 * m1 + f2 * m2 + f3 * m3);
            out[off_ker + (size_t)img * 10 + j] = expf(-sq);
        } else if (tid == 10) {
            // sampler: tanh(2->4) -> (4->2) -> softmax
            float t1[4];
            #pragma unroll
            for (int j = 0; j < 4; ++j)
                t1[j] = tanhf(f0 * sw1[j * 2] + f1 * sw1[j * 2 + 1] + sb1[j]);
            float s0 = sb2[0], s1v = sb2[1];
            #pragma unroll
            for (int j = 0; j < 4; ++j) { s0 += t1[j] * sw2[j]; s1v += t1[j] * sw2[4 + j]; }
            float mx = fmaxf(s0, s1v);
            float e0 = expf(s0 - mx), e1 = expf(s1v - mx);
            float inv = 1.f / (e0 + e1);
            out[off_samp + (size_t)img * 2 + 0] = e0 * inv;
            out[off_samp + (size_t)img * 2 + 1] = e1 * inv;
        } else {
            // estimator: tanh(2->8) -> tanh(8->4) -> (4->1)
            float e1a[8];
            #pragma unroll
            for (int j = 0; j < 8; ++j)
                e1a[j] = tanhf(f0 * ew1[j * 2] + f1 * ew1[j * 2 + 1] + eb1[j]);
            float rg = eb3[0];
            #pragma unroll
            for (int m = 0; m < 4; ++m) {
                float a = eb2[m];
                #pragma unroll
                for (int j = 0; j < 8; ++j) a += e1a[j] * ew2[m * 8 + j];
                rg += tanhf(a) * ew3[m];
            }
            out[off_reg + img] = rg;
        }
    }
}

// ---------------------------------------------------------------------------
// Kernel 3: fc1 (784->64) + relu + fc2 (64->4)
//   block = 256 threads = 4 waves; each wave owns 8 images, lane = fc1 output
// ---------------------------------------------------------------------------
__global__ __launch_bounds__(256) void k_fc(
    const float* __restrict__ flat, const float* __restrict__ wt,
    const float* __restrict__ fc1b, const float* __restrict__ fc2w,
    const float* __restrict__ fc2b, float* __restrict__ fc)
{
    const int tid  = threadIdx.x;
    const int lane = tid & 63;
    const int wv   = __builtin_amdgcn_readfirstlane(tid >> 6);  // wave-uniform
    const int img0 = blockIdx.x * 32 + wv * 8;
    const float* fl = flat + (size_t)img0 * 784;

    float acc[8];
    #pragma unroll
    for (int j = 0; j < 8; ++j) acc[j] = 0.f;

    #pragma unroll 4
    for (int k = 0; k < 784; ++k) {
        float w = wt[k * 64 + lane];       // coalesced, L2-hot (200 KB)
        #pragma unroll
        for (int j = 0; j < 8; ++j)
            acc[j] += fl[j * 784 + k] * w; // wave-uniform -> scalar loads
    }

    __shared__ float h[4][8][65];          // wave, img, out (pad to 65)
    float b = fc1b[lane];
    #pragma unroll
    for (int j = 0; j < 8; ++j)
        h[wv][j][lane] = fmaxf(acc[j] + b, 0.f);
    __syncthreads();

    if (tid < 128) {
        int im = tid >> 2;                 // 0..31 within block
        int c  = tid & 3;
        float a = fc2b[c];
        const float* hp = &h[im >> 3][im & 7][0];
        const float* wp = &fc2w[c * 64];
        #pragma unroll 8
        for (int o = 0; o < 64; ++o) a += hp[o] * wp[o];
        fc[(size_t)(blockIdx.x * 32 + im) * 4 + c] = a;
    }
}

// ---------------------------------------------------------------------------
// Kernel 4: deterministic BN statistics (1 block)
// ---------------------------------------------------------------------------
__global__ __launch_bounds__(256) void k_bnred(
    const float* __restrict__ fc, const float* __restrict__ g,
    const float* __restrict__ bb, float* __restrict__ bnp, int bsz)
{
    const int tid = threadIdx.x;
    float s = 0.f, ss = 0.f;
    for (int i = tid; i < bsz * 4; i += 256) {   // i&3 == tid&3 (256%4==0)
        float v = fc[i];
        s += v; ss += v * v;
    }
    __shared__ float rs[256], rss[256];
    rs[tid] = s; rss[tid] = ss;
    __syncthreads();
    for (int off = 128; off >= 4; off >>= 1) {   // offsets multiple of 4 keep channel
        if (tid < off) { rs[tid] += rs[tid + off]; rss[tid] += rss[tid + off]; }
        __syncthreads();
    }
    if (tid < 4) {
        float n = (float)bsz;
        float mu  = rs[tid] / n;
        float var = rss[tid] / n - mu * mu;
        float scale = g[tid] * rsqrtf(var + EPS_BN);
        bnp[tid]     = scale;
        bnp[4 + tid] = bb[tid] - mu * scale;
    }
}

// ---------------------------------------------------------------------------
// Kernel 5: apply BN -> logits
// ---------------------------------------------------------------------------
__global__ __launch_bounds__(256) void k_bnapply(
    const float* __restrict__ fc, const float* __restrict__ bnp,
    float* __restrict__ out, int n)
{
    int i = blockIdx.x * 256 + threadIdx.x;
    if (i < n) {
        int c = i & 3;
        out[i] = fc[i] * bnp[c] + bnp[4 + c];
    }
}

// ---------------------------------------------------------------------------
extern "C" void kernel_launch(void* const* d_in, const int* in_sizes, int n_in,
                              void* d_out, int out_size, void* d_ws, size_t ws_size,
                              hipStream_t stream) {
    const float* x     = (const float*)d_in[0];
    const float* c1w   = (const float*)d_in[1];
    const float* c1b   = (const float*)d_in[2];
    const float* c2w   = (const float*)d_in[3];
    const float* c2b   = (const float*)d_in[4];
    const float* fc1w  = (const float*)d_in[5];
    const float* fc1b  = (const float*)d_in[6];
    const float* fc2w  = (const float*)d_in[7];
    const float* fc2b  = (const float*)d_in[8];
    const float* bng   = (const float*)d_in[9];
    const float* bnb   = (const float*)d_in[10];
    const float* sw1   = (const float*)d_in[11];
    const float* sb1   = (const float*)d_in[12];
    const float* sw2   = (const float*)d_in[13];
    const float* sb2   = (const float*)d_in[14];
    const float* ew1   = (const float*)d_in[15];
    const float* eb1   = (const float*)d_in[16];
    const float* ew2   = (const float*)d_in[17];
    const float* eb2   = (const float*)d_in[18];
    const float* ew3   = (const float*)d_in[19];
    const float* eb3   = (const float*)d_in[20];
    const float* mem   = (const float*)d_in[21];

    const int bsz = in_sizes[0] / 784;     // 8192
    float* out = (float*)d_out;
    float* ws  = (float*)d_ws;

    float* wt   = ws;                              // 784*64 = 50176 floats
    float* flat = ws + 50176;                      // bsz*784
    float* fc   = flat + (size_t)bsz * 784;        // bsz*4
    float* bnp  = fc + (size_t)bsz * 4;            // 8

    k_transpose<<<196, 256, 0, stream>>>(fc1w, wt);
    k_conv<<<bsz, 256, 0, stream>>>(x, c1w, c1b, c2w, c2b,
                                    sw1, sb1, sw2, sb2,
                                    ew1, eb1, ew2, eb2, ew3, eb3, mem,
                                    flat, out, bsz);
    k_fc<<<bsz / 32, 256, 0, stream>>>(flat, wt, fc1b, fc2w, fc2b, fc);
    k_bnred<<<1, 256, 0, stream>>>(fc, bng, bnb, bnp, bsz);
    k_bnapply<<<(bsz * 4 + 255) / 256, 256, 0, stream>>>(fc, bnp, out, bsz * 4);
}

// Round 2
// 155.966 us; speedup vs baseline: 2.5886x; 2.5886x over previous
//
#include <hip/hip_runtime.h>
#include <math.h>

#define EPS_BN 1e-5f
#define IMGS 4

// ---------------------------------------------------------------------------
// Kernel 1: transpose fc1_w (64,784) -> wt (784,64) so fc1 reads coalesce
// ---------------------------------------------------------------------------
__global__ __launch_bounds__(256) void k_transpose(const float* __restrict__ w,
                                                   float* __restrict__ wt) {
    int t = blockIdx.x * 256 + threadIdx.x;
    if (t < 784 * 64) {
        int k = t >> 6;
        int o = t & 63;
        wt[t] = w[o * 784 + k];
    }
}

// ---------------------------------------------------------------------------
// Kernel 2 (mega): conv1+pool, conv2+pool, heads, fc1+relu, fc2 — 4 img/block
// ---------------------------------------------------------------------------
__global__ __launch_bounds__(256, 3) void k_fused(
    const float* __restrict__ x,
    const float* __restrict__ c1w, const float* __restrict__ c1b,
    const float* __restrict__ c2w, const float* __restrict__ c2b,
    const float* __restrict__ wt,  const float* __restrict__ fc1b,
    const float* __restrict__ fc2w, const float* __restrict__ fc2b,
    const float* __restrict__ sw1, const float* __restrict__ sb1,
    const float* __restrict__ sw2, const float* __restrict__ sb2,
    const float* __restrict__ ew1, const float* __restrict__ eb1,
    const float* __restrict__ ew2, const float* __restrict__ eb2,
    const float* __restrict__ ew3, const float* __restrict__ eb3,
    const float* __restrict__ mem,
    float* __restrict__ fc, float* __restrict__ out, int bsz)
{
    // sxs2: first the 28x28 input (pitch 29), later reused as flat row (784)
    __shared__ float sxs2[IMGS][812];
    __shared__ float s1[IMGS][8][210];     // 14 rows x pitch 15 per channel
    __shared__ float h[IMGS][65];          // fc1 hidden, padded

    const int tid  = threadIdx.x;
    const int img0 = blockIdx.x * IMGS;

    // ---- stage 4 input images into LDS (padded pitch 29)
    const float* xb = x + (size_t)img0 * 784;
    for (int i = tid; i < IMGS * 784; i += 256) {
        int im = i / 784;
        int j  = i - im * 784;
        sxs2[im][(j / 28) * 29 + (j % 28)] = xb[i];
    }
    __syncthreads();

    // ---- conv1 3x3 SAME (1->8) + relu + 2x2 pool. task = (img, pooled pos)
    for (int t = tid; t < IMGS * 196; t += 256) {
        int im  = t / 196;
        int pos = t - im * 196;
        int py  = pos / 14, px = pos - py * 14;
        int br  = 2 * py - 1, bc = 2 * px - 1;
        const float* sp = &sxs2[im][0];
        float win[4][4];
        #pragma unroll
        for (int wy = 0; wy < 4; ++wy) {
            int iy = br + wy;
            bool oy = (unsigned)iy < 28u;
            #pragma unroll
            for (int wx = 0; wx < 4; ++wx) {
                int ix = bc + wx;
                win[wy][wx] = (oy && (unsigned)ix < 28u) ? sp[iy * 29 + ix] : 0.f;
            }
        }
        #pragma unroll
        for (int c = 0; c < 8; ++c) {
            const float* wp = &c1w[c * 9];   // uniform -> scalar loads
            float bb = c1b[c];
            float a00 = bb, a01 = bb, a10 = bb, a11 = bb;
            #pragma unroll
            for (int ky = 0; ky < 3; ++ky) {
                #pragma unroll
                for (int kx = 0; kx < 3; ++kx) {
                    float wv = wp[ky * 3 + kx];
                    a00 += win[ky][kx]         * wv;
                    a01 += win[ky][kx + 1]     * wv;
                    a10 += win[ky + 1][kx]     * wv;
                    a11 += win[ky + 1][kx + 1] * wv;
                }
            }
            float m = fmaxf(fmaxf(a00, a01), fmaxf(a10, a11));
            s1[im][c][py * 15 + px] = fmaxf(m, 0.f);
        }
    }
    __syncthreads();

    // ---- conv2 3x3 SAME (8->16) + relu + pool. wave = image, lane = position
    {
        const int im = tid >> 6;
        const int p  = tid & 63;
        if (p < 49) {
            int py = p / 7, px = p - py * 7;
            int br = 2 * py - 1, bc = 2 * px - 1;
            float acc[16][4];
            #pragma unroll
            for (int c = 0; c < 16; ++c) {
                float bb = c2b[c];
                acc[c][0] = bb; acc[c][1] = bb; acc[c][2] = bb; acc[c][3] = bb;
            }
            for (int ic = 0; ic < 8; ++ic) {
                const float* sp = &s1[im][ic][0];
                float win[4][4];
                #pragma unroll
                for (int wy = 0; wy < 4; ++wy) {
                    int iy = br + wy;
                    bool oy = (unsigned)iy < 14u;
                    #pragma unroll
                    for (int wx = 0; wx < 4; ++wx) {
                        int ix = bc + wx;
                        win[wy][wx] = (oy && (unsigned)ix < 14u) ? sp[iy * 15 + ix] : 0.f;
                    }
                }
                #pragma unroll
                for (int c = 0; c < 16; ++c) {
                    const float* wp = &c2w[(c * 8 + ic) * 9];  // uniform -> s_load
                    #pragma unroll
                    for (int ky = 0; ky < 3; ++ky) {
                        #pragma unroll
                        for (int kx = 0; kx < 3; ++kx) {
                            float wv = wp[ky * 3 + kx];
                            acc[c][0] += win[ky][kx]         * wv;
                            acc[c][1] += win[ky][kx + 1]     * wv;
                            acc[c][2] += win[ky + 1][kx]     * wv;
                            acc[c][3] += win[ky + 1][kx + 1] * wv;
                        }
                    }
                }
            }
            float* s2i = &sxs2[im][0];       // reuse sx region as flat row
            #pragma unroll
            for (int c = 0; c < 16; ++c) {
                float m = fmaxf(fmaxf(acc[c][0], acc[c][1]),
                                fmaxf(acc[c][2], acc[c][3]));
                s2i[c * 49 + p] = fmaxf(m, 0.f);
            }
        }
    }
    __syncthreads();

    // ---- tiny heads: lanes 0..11 of each wave handle that wave's image
    {
        const int im   = tid >> 6;
        const int lane = tid & 63;
        const int gimg = img0 + im;
        const float* s2i = &sxs2[im][0];
        if (lane < 12) {
            const float f0 = s2i[0], f1 = s2i[1], f2 = s2i[2], f3 = s2i[3];
            const int off_samp = bsz * 4;
            const int off_reg  = bsz * 6;
            const int off_ker  = bsz * 7;
            if (lane < 10) {
                int j = lane;
                float m0 = mem[j * 4 + 0], m1 = mem[j * 4 + 1];
                float m2 = mem[j * 4 + 2], m3 = mem[j * 4 + 3];
                float sq = f0 * f0 + f1 * f1 + f2 * f2 + f3 * f3
                         + m0 * m0 + m1 * m1 + m2 * m2 + m3 * m3
                         - 2.f * (f0 * m0 + f1 * m1 + f2 * m2 + f3 * m3);
                out[off_ker + (size_t)gimg * 10 + j] = expf(-sq);
            } else if (lane == 10) {
                float t1[4];
                #pragma unroll
                for (int j = 0; j < 4; ++j)
                    t1[j] = tanhf(f0 * sw1[j * 2] + f1 * sw1[j * 2 + 1] + sb1[j]);
                float s0 = sb2[0], s1v = sb2[1];
                #pragma unroll
                for (int j = 0; j < 4; ++j) { s0 += t1[j] * sw2[j]; s1v += t1[j] * sw2[4 + j]; }
                float mx = fmaxf(s0, s1v);
                float e0 = expf(s0 - mx), e1 = expf(s1v - mx);
                float inv = 1.f / (e0 + e1);
                out[off_samp + (size_t)gimg * 2 + 0] = e0 * inv;
                out[off_samp + (size_t)gimg * 2 + 1] = e1 * inv;
            } else {
                float e1a[8];
                #pragma unroll
                for (int j = 0; j < 8; ++j)
                    e1a[j] = tanhf(f0 * ew1[j * 2] + f1 * ew1[j * 2 + 1] + eb1[j]);
                float rg = eb3[0];
                #pragma unroll
                for (int m = 0; m < 4; ++m) {
                    float a = eb2[m];
                    #pragma unroll
                    for (int j = 0; j < 8; ++j) a += e1a[j] * ew2[m * 8 + j];
                    rg += tanhf(a) * ew3[m];
                }
                out[off_reg + gimg] = rg;
            }
        }
    }

    // ---- fc1: lane = output neuron, wave = image; flat row broadcast from LDS
    {
        const int im = tid >> 6;
        const int o  = tid & 63;
        const float* s2i = &sxs2[im][0];
        float a = 0.f;
        #pragma unroll 4
        for (int k = 0; k < 784; ++k)
            a += s2i[k] * wt[k * 64 + o];    // s2i broadcast, wt coalesced (L2)
        h[im][o] = fmaxf(a + fc1b[o], 0.f);
    }
    __syncthreads();

    // ---- fc2: 16 threads, each one (img, channel)
    if (tid < 16) {
        int im = tid >> 2, c = tid & 3;
        float a = fc2b[c];
        const float* hp = &h[im][0];
        const float* wp = &fc2w[c * 64];
        #pragma unroll 8
        for (int o = 0; o < 64; ++o) a += hp[o] * wp[o];
        fc[(size_t)(img0 + im) * 4 + c] = a;
    }
}

// ---------------------------------------------------------------------------
// Kernel 3: BN stats stage 1 — 64 blocks, deterministic partials
// ---------------------------------------------------------------------------
__global__ __launch_bounds__(256) void k_bnred1(
    const float* __restrict__ fc, float* __restrict__ partial, int bsz)
{
    const int tid = threadIdx.x;
    const int b   = blockIdx.x;
    const int n   = bsz * 4;
    const int chunk = n / 64;                 // 2048 for bsz=8192
    float s = 0.f, ss = 0.f;
    for (int i = b * chunk + tid; i < (b + 1) * chunk; i += 256) {
        float v = fc[i];
        s += v; ss += v * v;
    }
    __shared__ float rs[256], rss[256];
    rs[tid] = s; rss[tid] = ss;
    __syncthreads();
    for (int off = 128; off >= 4; off >>= 1) {
        if (tid < off) { rs[tid] += rs[tid + off]; rss[tid] += rss[tid + off]; }
        __syncthreads();
    }
    if (tid < 4) {
        partial[b * 8 + tid]     = rs[tid];
        partial[b * 8 + 4 + tid] = rss[tid];
    }
}

// ---------------------------------------------------------------------------
// Kernel 4: BN stats stage 2 — combine 64 partials -> scale/shift
// ---------------------------------------------------------------------------
__global__ __launch_bounds__(64) void k_bnred2(
    const float* __restrict__ partial, const float* __restrict__ g,
    const float* __restrict__ bb, float* __restrict__ bnp, int bsz)
{
    const int tid = threadIdx.x;
    if (tid < 4) {
        float s = 0.f, ss = 0.f;
        for (int b = 0; b < 64; ++b) {
            s  += partial[b * 8 + tid];
            ss += partial[b * 8 + 4 + tid];
        }
        float n = (float)bsz;
        float mu  = s / n;
        float var = ss / n - mu * mu;
        float scale = g[tid] * rsqrtf(var + EPS_BN);
        bnp[tid]     = scale;
        bnp[4 + tid] = bb[tid] - mu * scale;
    }
}

// ---------------------------------------------------------------------------
// Kernel 5: apply BN -> logits
// ---------------------------------------------------------------------------
__global__ __launch_bounds__(256) void k_bnapply(
    const float* __restrict__ fc, const float* __restrict__ bnp,
    float* __restrict__ out, int n)
{
    int i = blockIdx.x * 256 + threadIdx.x;
    if (i < n) {
        int c = i & 3;
        out[i] = fc[i] * bnp[c] + bnp[4 + c];
    }
}

// ---------------------------------------------------------------------------
extern "C" void kernel_launch(void* const* d_in, const int* in_sizes, int n_in,
                              void* d_out, int out_size, void* d_ws, size_t ws_size,
                              hipStream_t stream) {
    const float* x     = (const float*)d_in[0];
    const float* c1w   = (const float*)d_in[1];
    const float* c1b   = (const float*)d_in[2];
    const float* c2w   = (const float*)d_in[3];
    const float* c2b   = (const float*)d_in[4];
    const float* fc1w  = (const float*)d_in[5];
    const float* fc1b  = (const float*)d_in[6];
    const float* fc2w  = (const float*)d_in[7];
    const float* fc2b  = (const float*)d_in[8];
    const float* bng   = (const float*)d_in[9];
    const float* bnb   = (const float*)d_in[10];
    const float* sw1   = (const float*)d_in[11];
    const float* sb1   = (const float*)d_in[12];
    const float* sw2   = (const float*)d_in[13];
    const float* sb2   = (const float*)d_in[14];
    const float* ew1   = (const float*)d_in[15];
    const float* eb1   = (const float*)d_in[16];
    const float* ew2   = (const float*)d_in[17];
    const float* eb2   = (const float*)d_in[18];
    const float* ew3   = (const float*)d_in[19];
    const float* eb3   = (const float*)d_in[20];
    const float* mem   = (const float*)d_in[21];

    const int bsz = in_sizes[0] / 784;         // 8192
    float* out = (float*)d_out;
    float* ws  = (float*)d_ws;

    float* wt      = ws;                       // 50176 floats
    float* fc      = ws + 50176;               // bsz*4
    float* partial = fc + (size_t)bsz * 4;     // 64*8
    float* bnp     = partial + 512;            // 8

    k_transpose<<<196, 256, 0, stream>>>(fc1w, wt);
    k_fused<<<bsz / IMGS, 256, 0, stream>>>(x, c1w, c1b, c2w, c2b,
                                            wt, fc1b, fc2w, fc2b,
                                            sw1, sb1, sw2, sb2,
                                            ew1, eb1, ew2, eb2, ew3, eb3, mem,
                                            fc, out, bsz);
    k_bnred1<<<64, 256, 0, stream>>>(fc, partial, bsz);
    k_bnred2<<<1, 64, 0, stream>>>(partial, bng, bnb, bnp, bsz);
    k_bnapply<<<(bsz * 4 + 255) / 256, 256, 0, stream>>>(fc, bnp, out, bsz * 4);
}